// Round 2
// baseline (1350.918 us; speedup 1.0000x reference)
//
#include <hip/hip_runtime.h>
#include <hip/hip_bf16.h>
#include <math.h>

typedef __bf16 bf16;
typedef bf16 bf16x8 __attribute__((ext_vector_type(8)));
typedef bf16 bf16x4 __attribute__((ext_vector_type(4)));
typedef float f32x4 __attribute__((ext_vector_type(4)));

static constexpr int Bc = 32, L = 196, DM = 512, DI = 1024, DS = 16, DTR = 32, KC = 4;
static constexpr int Mrows = Bc * L; // 6272

__device__ __forceinline__ float sigf(float x) { return 1.0f / (1.0f + __expf(-x)); }
__device__ __forceinline__ float softplusf(float x) {
    return (x > 15.0f) ? x : __logf(1.0f + __expf(x));
}

// ---------------------------------------------------------------------------
// f32 -> bf16 conversion (4 elems/thread)
// ---------------------------------------------------------------------------
__global__ __launch_bounds__(256) void cvt_k(const float* __restrict__ in,
                                             bf16* __restrict__ out, int n4)
{
    int i = blockIdx.x * 256 + threadIdx.x;
    if (i >= n4) return;
    float4 v = ((const float4*)in)[i];
    bf16x4 o = {(bf16)v.x, (bf16)v.y, (bf16)v.z, (bf16)v.w};
    *(bf16x4*)(out + 4 * (size_t)i) = o;
}

// ---------------------------------------------------------------------------
// GEMM: C[M,N] = A[M,K] (row stride lda, bf16) * W[N,K]^T (bf16) (+bias f32)
// (+act)(+res). 128x128 tile, BK=32, 4 waves, each 64x64 via 4x4 MFMA 16x16x32.
// A-frag: lane holds A[m = lane&15][k = quad*8 + j]; B-frag same on W rows (n).
// C/D:    col(n) = lane&15, row(m) = quad*4 + reg   [m89/m91 verified]
// ---------------------------------------------------------------------------
#define LSTR 40  // LDS row stride in bf16 (32 data + 8 pad; 80B keeps 16B align)

template <int STORE_F32, int ACT, int RES_MODE>
__global__ __launch_bounds__(256) void gemm_bt(
    const bf16* __restrict__ A, int lda,
    const bf16* __restrict__ W,
    void* __restrict__ Cp,
    const float* __restrict__ bias,
    const float* __restrict__ res, int res_div,
    int M, int N, int K)
{
    __shared__ bf16 As[128 * LSTR];
    __shared__ bf16 Bs[128 * LSTR];
    const int t = threadIdx.x;
    const int m0 = blockIdx.y * 128;
    const int n0 = blockIdx.x * 128;
    const int lane = t & 63;
    const int w = t >> 6;
    const int wm = (w >> 1) * 64, wn = (w & 1) * 64;
    const int ml = lane & 15, quad = lane >> 4;

    f32x4 acc[4][4] = {};

    for (int k0 = 0; k0 < K; k0 += 32) {
#pragma unroll
        for (int v = 0; v < 2; ++v) {
            int vid = t * 2 + v;        // 0..511
            int row = vid >> 2;         // 0..127
            int kv = (vid & 3) * 8;     // 0,8,16,24
            bf16x8 av = *(const bf16x8*)(A + (size_t)(m0 + row) * lda + k0 + kv);
            *(bf16x8*)&As[row * LSTR + kv] = av;
            bf16x8 bv = {};
            if (n0 + row < N) bv = *(const bf16x8*)(W + (size_t)(n0 + row) * K + k0 + kv);
            *(bf16x8*)&Bs[row * LSTR + kv] = bv;
        }
        __syncthreads();
        bf16x8 af[4], bfr[4];
#pragma unroll
        for (int i = 0; i < 4; ++i)
            af[i] = *(const bf16x8*)&As[(wm + i * 16 + ml) * LSTR + quad * 8];
#pragma unroll
        for (int i = 0; i < 4; ++i)
            bfr[i] = *(const bf16x8*)&Bs[(wn + i * 16 + ml) * LSTR + quad * 8];
#pragma unroll
        for (int i = 0; i < 4; ++i)
#pragma unroll
            for (int j = 0; j < 4; ++j)
                acc[i][j] = __builtin_amdgcn_mfma_f32_16x16x32_bf16(af[i], bfr[j], acc[i][j], 0, 0, 0);
        __syncthreads();
    }

#pragma unroll
    for (int j = 0; j < 4; ++j) {
        int col = n0 + wn + j * 16 + ml;
        if (col >= N) continue;
        float bv = bias ? bias[col] : 0.0f;
#pragma unroll
        for (int i = 0; i < 4; ++i) {
#pragma unroll
            for (int r = 0; r < 4; ++r) {
                int row = m0 + wm + i * 16 + quad * 4 + r;
                float v = acc[i][j][r] + bv;
                if (ACT == 1) v = softplusf(v);
                if (RES_MODE == 1) v += res[(size_t)row * N + col];
                if (RES_MODE == 2) v += res[(size_t)(row / res_div) * N + col];
                if (STORE_F32) ((float*)Cp)[(size_t)row * N + col] = v;
                else           ((bf16*)Cp)[(size_t)row * N + col] = (bf16)v;
            }
        }
    }
}

// ---------------------------------------------------------------------------
// Row norm: one wave per 512-elem row. RMS_SILU=1: silu(rmsnorm(x)*w);
// RMS_SILU=0: layernorm(x)*w + b. fp32 in; out bf16 or f32.
// ---------------------------------------------------------------------------
template <int RMS_SILU, int OUT_F32>
__global__ __launch_bounds__(64) void norm_rows(
    const float* __restrict__ x, const float* __restrict__ w, const float* __restrict__ b,
    void* __restrict__ outp)
{
    int row = blockIdx.x, t = threadIdx.x;
    const float4* xr = (const float4*)(x + (size_t)row * DM);
    float4 v0 = xr[t], v1 = xr[64 + t];
    float vv[8] = {v0.x, v0.y, v0.z, v0.w, v1.x, v1.y, v1.z, v1.w};
    float s = 0.0f, ss = 0.0f;
#pragma unroll
    for (int e = 0; e < 8; ++e) { s += vv[e]; ss += vv[e] * vv[e]; }
#pragma unroll
    for (int m = 1; m < 64; m <<= 1) {
        s += __shfl_xor(s, m, 64);
        ss += __shfl_xor(ss, m, 64);
    }
    float mu, inv;
    if (RMS_SILU) { mu = 0.0f; inv = rsqrtf(ss * (1.0f / DM) + 1e-5f); }
    else {
        mu = s * (1.0f / DM);
        inv = rsqrtf(ss * (1.0f / DM) - mu * mu + 1e-5f);
    }
#pragma unroll
    for (int g = 0; g < 2; ++g) {
        int c0 = (g == 0) ? t * 4 : 256 + t * 4;
#pragma unroll
        for (int e = 0; e < 4; ++e) {
            int c = c0 + e;
            float val = (vv[g * 4 + e] - mu) * inv * w[c];
            if (RMS_SILU) val = val * sigf(val);
            else val += b[c];
            if (OUT_F32) ((float*)outp)[(size_t)row * DM + c] = val;
            else         ((bf16*)outp)[(size_t)row * DM + c] = (bf16)val;
        }
    }
}

// ---------------------------------------------------------------------------
// Depthwise causal conv (K=4) + bias + SiLU. Reads first DI cols of xz rows.
// ---------------------------------------------------------------------------
__global__ __launch_bounds__(256) void conv_silu_k(
    const bf16* __restrict__ xz, const float* __restrict__ cw, const float* __restrict__ cb,
    bf16* __restrict__ xi)
{
    int idx = blockIdx.x * 256 + threadIdx.x;
    if (idx >= Mrows * DI) return;
    int d = idx & (DI - 1);
    int r = idx >> 10;       // b*L + l
    int l = r % L;
    float w0 = cw[d * 4 + 0], w1 = cw[d * 4 + 1];
    float w2 = cw[d * 4 + 2], w3 = cw[d * 4 + 3];
    const bf16* base = xz + (size_t)r * (2 * DI) + d;
    float acc = cb[d];
    if (l >= 3) acc += (float)base[-3 * 2 * DI] * w0;
    if (l >= 2) acc += (float)base[-2 * 2 * DI] * w1;
    if (l >= 1) acc += (float)base[-1 * 2 * DI] * w2;
    acc += (float)base[0] * w3;
    xi[idx] = (bf16)(acc * sigf(acc));
}

// ---------------------------------------------------------------------------
// Selective scan: one thread per (b,d), 16 states in registers.
// y = (scan_y + D*xi) * silu(z), bf16 out.
// ---------------------------------------------------------------------------
__global__ __launch_bounds__(256) void scan_k(
    const bf16* __restrict__ dtb, const bf16* __restrict__ xib,
    const bf16* __restrict__ xzb, const bf16* __restrict__ dbcb,
    const float* __restrict__ Alog, const float* __restrict__ Dp,
    bf16* __restrict__ yb)
{
    int b = blockIdx.x >> 2;
    int d = ((blockIdx.x & 3) << 8) + threadIdx.x;
    float A[16], h[16];
#pragma unroll
    for (int n = 0; n < 16; ++n) {
        A[n] = -__expf(Alog[d * 16 + n]);
        h[n] = 0.0f;
    }
    float Dv = Dp[d];
    for (int l = 0; l < L; ++l) {
        size_t r = (size_t)b * L + l;
        float dtv = (float)dtb[r * DI + d];
        float xiv = (float)xib[r * DI + d];
        float zv = (float)xzb[r * 2 * DI + DI + d];
        const bf16* rowp = dbcb + r * 64;
        bf16x8 B0 = *(const bf16x8*)(rowp + 32);
        bf16x8 B1 = *(const bf16x8*)(rowp + 40);
        bf16x8 C0 = *(const bf16x8*)(rowp + 48);
        bf16x8 C1 = *(const bf16x8*)(rowp + 56);
        float Bf[16], Cf[16];
#pragma unroll
        for (int j = 0; j < 8; ++j) {
            Bf[j] = (float)B0[j]; Bf[8 + j] = (float)B1[j];
            Cf[j] = (float)C0[j]; Cf[8 + j] = (float)C1[j];
        }
        float dtxi = dtv * xiv, ya = 0.0f;
#pragma unroll
        for (int n = 0; n < 16; ++n) {
            float e = __expf(dtv * A[n]);
            h[n] = e * h[n] + dtxi * Bf[n];
            ya += h[n] * Cf[n];
        }
        float yv = (ya + Dv * xiv) * (zv * sigf(zv));
        yb[r * DI + d] = (bf16)yv;
    }
}

// ---------------------------------------------------------------------------
// Pair maxpool over L_IN=392 -> 196 (f32 in, bf16 out)
// ---------------------------------------------------------------------------
__global__ __launch_bounds__(256) void maxpool_k(const float* __restrict__ m, bf16* __restrict__ out)
{
    int idx = blockIdx.x * 256 + threadIdx.x;
    if (idx >= Mrows * DM) return;
    int c = idx & (DM - 1);
    int r = idx >> 9;  // b*L + l
    int l = r % L, b = r / L;
    float a0 = m[((size_t)b * 392 + 2 * l) * DM + c];
    float a1 = m[((size_t)b * 392 + 2 * l + 1) * DM + c];
    out[idx] = (bf16)fmaxf(a0, a1);
}

extern "C" void kernel_launch(void* const* d_in, const int* in_sizes, int n_in,
                              void* d_out, int out_size, void* d_ws, size_t ws_size,
                              hipStream_t stream)
{
    (void)in_sizes; (void)n_in; (void)out_size; (void)ws_size;
    const float* motion = (const float*)d_in[0];
    const float* embed  = (const float*)d_in[1];
    const float* w1     = (const float*)d_in[2];
    const float* b1     = (const float*)d_in[3];
    const float* rmsw   = (const float*)d_in[4];
    const float* w2     = (const float*)d_in[5];
    const float* b2     = (const float*)d_in[6];
    const float* lnw    = (const float*)d_in[7];
    const float* lnb    = (const float*)d_in[8];
    const float* inw    = (const float*)d_in[9];
    const float* convw  = (const float*)d_in[10];
    const float* convb  = (const float*)d_in[11];
    const float* xprojw = (const float*)d_in[12];
    const float* dtw    = (const float*)d_in[13];
    const float* dtbias = (const float*)d_in[14];
    const float* Alog   = (const float*)d_in[15];
    const float* Dpar   = (const float*)d_in[16];
    const float* outw   = (const float*)d_in[17];
    const float* lnfw   = (const float*)d_in[18];
    const float* lnfb   = (const float*)d_in[19];

    char* ws = (char*)d_ws;
    float* x_f    = (float*)(ws + 0);          // 6272*512 f32
    bf16*  h_b    = (bf16*)(ws + 12845056);    // 6272*512 bf16
    bf16*  xz_b   = (bf16*)(ws + 19267584);    // 6272*2048 bf16
    bf16*  xi_b   = (bf16*)(ws + 44957696);    // 6272*1024 bf16
    bf16*  dbc_b  = (bf16*)(ws + 57802752);    // 6272*64 bf16
    bf16*  dtbuf  = (bf16*)(ws + 58605568);    // 6272*1024 bf16
    bf16*  y_b    = (bf16*)(ws + 71450624);    // 6272*1024 bf16
    bf16*  w1b    = (bf16*)(ws + 84295680);    // 512*512
    bf16*  w2b    = (bf16*)(ws + 84819968);    // 512*512
    bf16*  inwb   = (bf16*)(ws + 85344256);    // 4*2048*512
    bf16*  xprojb = (bf16*)(ws + 93732864);    // 4*64*1024
    bf16*  dtwb   = (bf16*)(ws + 94257152);    // 4*1024*32
    bf16*  outwb  = (bf16*)(ws + 94519296);    // 4*512*1024
    bf16*  pool   = xi_b;                      // reuse before layer loop

    dim3 blk(256);

    // Weight conversions f32 -> bf16
    auto cvt = [&](const float* src, bf16* dst, int n) {
        cvt_k<<<(n / 4 + 255) / 256, blk, 0, stream>>>(src, dst, n / 4);
    };
    cvt(w1, w1b, DM * DM);
    cvt(w2, w2b, DM * DM);
    cvt(inw, inwb, 4 * 2 * DI * DM);
    cvt(xprojw, xprojb, 4 * 64 * DI);
    cvt(dtw, dtwb, 4 * DI * DTR);
    cvt(outw, outwb, 4 * DM * DI);

    // Prologue
    maxpool_k<<<(Mrows * DM + 255) / 256, blk, 0, stream>>>(motion, pool);
    gemm_bt<1, 0, 0><<<dim3(4, 49), blk, 0, stream>>>(pool, DM, w1b, x_f, b1, nullptr, 1, Mrows, DM, DM);
    norm_rows<1, 0><<<Mrows, 64, 0, stream>>>(x_f, rmsw, nullptr, h_b);
    gemm_bt<1, 0, 2><<<dim3(4, 49), blk, 0, stream>>>(h_b, DM, w2b, x_f, b2, embed, L, Mrows, DM, DM);

    for (int i = 0; i < 4; ++i) {
        norm_rows<0, 0><<<Mrows, 64, 0, stream>>>(x_f, lnw + i * DM, lnb + i * DM, h_b);
        gemm_bt<0, 0, 0><<<dim3(16, 49), blk, 0, stream>>>(
            h_b, DM, inwb + (size_t)i * 2 * DI * DM, xz_b, nullptr, nullptr, 1, Mrows, 2 * DI, DM);
        conv_silu_k<<<(Mrows * DI + 255) / 256, blk, 0, stream>>>(
            xz_b, convw + i * DI * KC, convb + i * DI, xi_b);
        gemm_bt<0, 0, 0><<<dim3(1, 49), blk, 0, stream>>>(
            xi_b, DI, xprojb + (size_t)i * 64 * DI, dbc_b, nullptr, nullptr, 1, Mrows, 64, DI);
        gemm_bt<0, 1, 0><<<dim3(8, 49), blk, 0, stream>>>(
            dbc_b, 64, dtwb + (size_t)i * DI * DTR, dtbuf, dtbias + i * DI, nullptr, 1, Mrows, DI, DTR);
        scan_k<<<128, blk, 0, stream>>>(
            dtbuf, xi_b, xz_b, dbc_b, Alog + i * DI * DS, Dpar + i * DI, y_b);
        gemm_bt<1, 0, 1><<<dim3(4, 49), blk, 0, stream>>>(
            y_b, DI, outwb + (size_t)i * DM * DI, x_f, nullptr, x_f, 1, Mrows, DM, DI);
    }
    norm_rows<0, 1><<<Mrows, 64, 0, stream>>>(x_f, lnfw, lnfb, (float*)d_out);
}